// Round 1
// baseline (3455.968 us; speedup 1.0000x reference)
//
#include <hip/hip_runtime.h>
#include <cstdint>
#include <cstddef>

// ============================================================================
// LSTM forecaster, MI355X — R5: interleaved-gate MFMA (operand-swapped) +
// wf[2] weight multiplexing. Evidence from R4 counters: step=3.42us with
// MfmaUtil 3.2%; modeled LDS A-read floor 2300 cyc/step (16 waves each re-
// reading the full 18KB A tile) + ex[] exchange (bank-conflict source).
// R5: 512-thr blocks, 8 waves, each wave owns 8 features x 4 gates via TWO
// interleaved weight tiles (rows = f_local*4+gate). mfma(wf, af) puts the
// 4 gates of one (feature,batch) into the 4 acc regs -> gate math is pure
// per-lane VALU, no LDS exchange, ONE barrier/step (A double-buffered).
// Each ds_read_b128 of A feeds 2 MFMAs -> A-traffic halved.
// Comm scheme unchanged: bf16 NaN sentinel, 8B agent-scope relaxed atomics.
// ============================================================================

typedef __bf16 bf16x8 __attribute__((ext_vector_type(8)));
typedef float  f32x4  __attribute__((ext_vector_type(4)));

static constexpr unsigned long long SENT = 0x7FC07FC07FC07FC0ULL;  // 4x bf16 NaN

// ---- workspace layout (bytes) ----
static constexpr size_t SZ_HALL = (size_t)705 * 128 * 512 * 2;  // h slots 0..704
static constexpr size_t SZ_WCAT = (size_t)2048 * 576 * 2;       // [Whh | Wfuse] bf16
static constexpr size_t SZ_WIH  = (size_t)2048 * 512 * 2;       // Wih bf16 (AR phase)
static constexpr size_t SZ_DECW = (size_t)64 * 512 * 2;         // dec_W bf16
static constexpr size_t SZ_XT   = (size_t)512 * 128 * 64 * 2;   // x transposed [t][b][c]
static constexpr size_t OFF_HALL = 0;
static constexpr size_t OFF_WCAT = OFF_HALL + SZ_HALL;
static constexpr size_t OFF_WIH  = OFF_WCAT + SZ_WCAT;
static constexpr size_t OFF_DECW = OFF_WIH + SZ_WIH;
static constexpr size_t OFF_XT   = OFF_DECW + SZ_DECW;
static constexpr size_t OFF_B2   = OFF_XT + SZ_XT;              // 2048 f32
static constexpr size_t OFF_BAR_ = OFF_B2 + 2048 * 4;           // b_ar 2048 f32
static constexpr size_t WS_NEEDED = OFF_BAR_ + 2048 * 4;

__device__ __forceinline__ float sigm(float x) { return 1.f / (1.f + __expf(-x)); }
__device__ __forceinline__ float tanh_fast(float x) {
  return 1.f - 2.f / (__expf(2.f * x) + 1.f);  // correct +/-1 limits on over/underflow
}

// ---------------------------------------------------------------------------
// setup0: conversions + h slot0 zeros + h slots 1..704 NaN sentinel fill.
// ---------------------------------------------------------------------------
__global__ void __launch_bounds__(256)
setup0(const float* __restrict__ x, const float* __restrict__ Wih,
       const float* __restrict__ Whh, const float* __restrict__ bih,
       const float* __restrict__ bhh, const float* __restrict__ decW,
       __bf16* __restrict__ xT, __bf16* __restrict__ Wih_bf,
       __bf16* __restrict__ Wcat, __bf16* __restrict__ decW_bf,
       float* __restrict__ b_ar, __bf16* __restrict__ h_all)
{
  size_t gid = (size_t)blockIdx.x * blockDim.x + threadIdx.x;
  size_t gsz = (size_t)gridDim.x * blockDim.x;
  for (size_t i = gid; i < 4194304u; i += gsz) {          // xT[t][b][c] = x[b][t][c]
    size_t t = i >> 13, b = (i >> 6) & 127u, c = i & 63u;
    xT[i] = (__bf16)x[(b * 512 + t) * 64 + c];
  }
  for (size_t i = gid; i < 1048576u; i += gsz) Wih_bf[i] = (__bf16)Wih[i];
  for (size_t i = gid; i < 1048576u; i += gsz) {
    size_t r = i >> 9, k = i & 511u;
    Wcat[r * 576 + k] = (__bf16)Whh[i];                   // cols 0..511 = Whh
  }
  for (size_t i = gid; i < 32768u; i += gsz) decW_bf[i] = (__bf16)decW[i];
  for (size_t i = gid; i < 2048u; i += gsz) b_ar[i] = bih[i] + bhh[i];
  unsigned long long* hp = (unsigned long long*)h_all;
  for (size_t i = gid; i < 16384u; i += gsz) hp[i] = 0ULL;               // slot 0 = 0
  for (size_t i = 16384u + gid; i < 11550720u; i += gsz) hp[i] = SENT;   // slots 1..704
}

// ---------------------------------------------------------------------------
// setup1: Wfuse = Wih @ enc_W -> Wcat cols 512..575 ; b2 = bih+bhh+Wih@enc_b
// ---------------------------------------------------------------------------
__global__ void __launch_bounds__(64)
setup1(const float* __restrict__ Wih, const float* __restrict__ encW,
       const float* __restrict__ encb, const float* __restrict__ bih,
       const float* __restrict__ bhh, __bf16* __restrict__ Wcat,
       float* __restrict__ b2)
{
  int r = blockIdx.x;        // 0..2047
  int c = threadIdx.x;       // 0..63
  const float* wr = Wih + (size_t)r * 512;
  float acc = 0.f;
  for (int k = 0; k < 512; ++k) acc += wr[k] * encW[(size_t)k * 64 + c];
  Wcat[(size_t)r * 576 + 512 + c] = (__bf16)acc;
  float p = 0.f;
  for (int kk = 0; kk < 8; ++kk) { int k = kk * 64 + c; p += wr[k] * encb[k]; }
  for (int off = 32; off > 0; off >>= 1) p += __shfl_down(p, off);
  if (c == 0) b2[r] = bih[r] + bhh[r] + p;
}

// ---------------------------------------------------------------------------
// One LSTM step. block = 512 thr (8 waves). Wave wv owns features
// f0+wv*8 .. +8 as TWO interleaved weight tiles (tile t2: rows =
// (f_local<<2)|gate, f_local = feature t2*4+quad). mfma(wf, af):
//   D reg axis  = weight row (quad*4 + r) -> gate = r, f_local = quad
//   D col axis  = activation row (n16)    -> batch
// so acc[t2] = {i,f,g,o} preacts of ONE (feature,batch): gate math in-reg.
// Publish: shfl quad-gather -> 8B piece; lanes 0..31 store (2 pieces/batch).
// A is double-buffered -> one __syncthreads per step (write of buf b at
// step t+2 is ordered after barrier(t+1); reads of buf b at t end before it).
// ---------------------------------------------------------------------------
template<bool MAIN>
__device__ __forceinline__ void lstm_step(
    unsigned t, int tid, int wv, int lane, int n16, int quad, int b0, int f0,
    const bf16x8 (&wf)[2][18], const f32x4& bv0, const f32x4& bv1,
    __bf16* __restrict__ h_all, const __bf16* __restrict__ xT,
    float& c0, float& c1, __bf16 (&A)[16][584])
{
  // ---- x prefetch (overlaps the poll) ----
  uint4 xv;
  if (MAIN && tid < 128)
    xv = *(const uint4*)(xT + (size_t)(t - 1) * 8192 +
                         (size_t)(b0 + (tid >> 3)) * 64 + (tid & 7) * 8);

  // ---- poll h_{t-1}: 4 x 8B pieces per thread, selective re-load ----
  const unsigned long long* src = (const unsigned long long*)
      (h_all + (size_t)(t - 1) * 65536 + (size_t)(b0 + (tid >> 5)) * 512) +
      (size_t)(tid & 31) * 4;
  unsigned long long v0 = __hip_atomic_load(src,     __ATOMIC_RELAXED, __HIP_MEMORY_SCOPE_AGENT);
  unsigned long long v1 = __hip_atomic_load(src + 1, __ATOMIC_RELAXED, __HIP_MEMORY_SCOPE_AGENT);
  unsigned long long v2 = __hip_atomic_load(src + 2, __ATOMIC_RELAXED, __HIP_MEMORY_SCOPE_AGENT);
  unsigned long long v3 = __hip_atomic_load(src + 3, __ATOMIC_RELAXED, __HIP_MEMORY_SCOPE_AGENT);
  while (v0 == SENT || v1 == SENT || v2 == SENT || v3 == SENT) {
    if (v0 == SENT) v0 = __hip_atomic_load(src,     __ATOMIC_RELAXED, __HIP_MEMORY_SCOPE_AGENT);
    if (v1 == SENT) v1 = __hip_atomic_load(src + 1, __ATOMIC_RELAXED, __HIP_MEMORY_SCOPE_AGENT);
    if (v2 == SENT) v2 = __hip_atomic_load(src + 2, __ATOMIC_RELAXED, __HIP_MEMORY_SCOPE_AGENT);
    if (v3 == SENT) v3 = __hip_atomic_load(src + 3, __ATOMIC_RELAXED, __HIP_MEMORY_SCOPE_AGENT);
  }

  // ---- stage A (batch = tid>>5, feats (tid&31)*16 .. +16) ----
  {
    unsigned long long* ad = (unsigned long long*)&A[tid >> 5][(tid & 31) * 16];
    ad[0] = v0; ad[1] = v1; ad[2] = v2; ad[3] = v3;
  }
  if (MAIN && tid < 128)
    *(uint4*)(&A[tid >> 3][512 + (tid & 7) * 8]) = xv;
  __syncthreads();

  // ---- MFMA: one A-fragment read feeds both weight tiles ----
  f32x4 a0 = bv0, a1 = bv1;
  const __bf16* arow = &A[n16][quad * 8];
  #pragma unroll
  for (int kc = 0; kc < (MAIN ? 18 : 16); ++kc) {
    bf16x8 af = *(const bf16x8*)(arow + kc * 32);
    a0 = __builtin_amdgcn_mfma_f32_16x16x32_bf16(wf[0][kc], af, a0, 0, 0, 0);
    a1 = __builtin_amdgcn_mfma_f32_16x16x32_bf16(wf[1][kc], af, a1, 0, 0, 0);
  }

  // ---- gates in registers: acc = {i,f,g,o} of (feature, batch=n16) ----
  float ig0 = sigm(a0[0]), gg0 = tanh_fast(a0[2]), og0 = sigm(a0[3]);
  float ig1 = sigm(a1[0]), gg1 = tanh_fast(a1[2]), og1 = sigm(a1[3]);
  float c2a, c2b;
  if (MAIN) {
    float fg0 = sigm(a0[1]), fg1 = sigm(a1[1]);
    c2a = fg0 * c0 + ig0 * gg0; c0 = c2a;
    c2b = fg1 * c1 + ig1 * gg1; c1 = c2b;
  } else {
    c2a = ig0 * gg0;            // AR: zero state
    c2b = ig1 * gg1;
  }
  unsigned hb0 = __builtin_bit_cast(unsigned short, (__bf16)(og0 * tanh_fast(c2a)));
  unsigned hb1 = __builtin_bit_cast(unsigned short, (__bf16)(og1 * tanh_fast(c2b)));

  // ---- pack 4 features (quad-gather via shfl) and publish ----
  unsigned long long pk0 = 0, pk1 = 0;
  #pragma unroll
  for (int q = 0; q < 4; ++q) {
    pk0 |= (unsigned long long)(unsigned short)__shfl((int)hb0, q * 16 + n16) << (16 * q);
    pk1 |= (unsigned long long)(unsigned short)__shfl((int)hb1, q * 16 + n16) << (16 * q);
  }
  if (lane < 32) {
    unsigned long long pk = quad ? pk1 : pk0;       // quad = 0/1 here
    unsigned long long* dst = (unsigned long long*)
        (h_all + (size_t)t * 65536 + (size_t)(b0 + n16) * 512 + f0 + wv * 8) + quad;
    __hip_atomic_store(dst, pk, __ATOMIC_RELAXED, __HIP_MEMORY_SCOPE_AGENT);
  }
}

__global__ void __launch_bounds__(512, 2)
lstm_persist(const __bf16* __restrict__ xT, const __bf16* __restrict__ Wcat,
             const __bf16* __restrict__ Wih_bf, const float* __restrict__ b2,
             const float* __restrict__ b_ar, __bf16* __restrict__ h_all)
{
  const int bid = blockIdx.x;                  // 64 blocks
  const int g = bid & 7, sub = bid >> 3;       // group g: blocks {g, 8+g, ...}
  const int b0 = g * 16, f0 = sub * 64;
  const int tid = threadIdx.x;
  const int wv = tid >> 6, lane = tid & 63;
  const int n16 = lane & 15, quad = lane >> 4;

  __shared__ __align__(16) __bf16 Abuf[2][16][584];  // double-buffered A tile

  // persistent weight fragments, interleaved rows: lane n16 loads global row
  // gate*512 + f0 + wv*8 + t2*4 + f_local  with gate=n16&3, f_local=n16>>2.
  bf16x8 wf[2][18];
  f32x4 bv0, bv1;
  {
    const int gate = n16 & 3, fl = n16 >> 2;
    #pragma unroll
    for (int t2 = 0; t2 < 2; ++t2) {
      const __bf16* wrow = Wcat +
          (size_t)(gate * 512 + f0 + wv * 8 + t2 * 4 + fl) * 576 + quad * 8;
      #pragma unroll
      for (int kc = 0; kc < 18; ++kc) wf[t2][kc] = *(const bf16x8*)(wrow + kc * 32);
    }
    const int fb = f0 + wv * 8 + quad;
    bv0 = f32x4{b2[fb],     b2[512 + fb],     b2[1024 + fb],     b2[1536 + fb]};
    bv1 = f32x4{b2[fb + 4], b2[512 + fb + 4], b2[1024 + fb + 4], b2[1536 + fb + 4]};
  }

  float c0 = 0.f, c1 = 0.f;   // cell state of this lane's two features

  for (unsigned t = 1; t <= 512; ++t)
    lstm_step<true>(t, tid, wv, lane, n16, quad, b0, f0, wf, bv0, bv1,
                    h_all, xT, c0, c1, Abuf[t & 1]);

  { // AR phase: h feeds Wih with zero recurrent state
    const int gate = n16 & 3, fl = n16 >> 2;
    #pragma unroll
    for (int t2 = 0; t2 < 2; ++t2) {
      const __bf16* wrow = Wih_bf +
          (size_t)(gate * 512 + f0 + wv * 8 + t2 * 4 + fl) * 512 + quad * 8;
      #pragma unroll
      for (int kc = 0; kc < 16; ++kc) wf[t2][kc] = *(const bf16x8*)(wrow + kc * 32);
    }
    const int fb = f0 + wv * 8 + quad;
    bv0 = f32x4{b_ar[fb],     b_ar[512 + fb],     b_ar[1024 + fb],     b_ar[1536 + fb]};
    bv1 = f32x4{b_ar[fb + 4], b_ar[512 + fb + 4], b_ar[1024 + fb + 4], b_ar[1536 + fb + 4]};
  }
  for (unsigned t = 513; t <= 704; ++t)
    lstm_step<false>(t, tid, wv, lane, n16, quad, b0, f0, wf, bv0, bv1,
                     h_all, xT, c0, c1, Abuf[t & 1]);
}

// ---------------------------------------------------------------------------
// final_proj: out[b][j][c] = h_slot[j+2][b][:] @ dec_W.T + dec_b, j=0..702.
// ---------------------------------------------------------------------------
__global__ void __launch_bounds__(256)
final_proj(const __bf16* __restrict__ h_all, const __bf16* __restrict__ decW_bf,
           const float* __restrict__ decb, float* __restrict__ out)
{
  const int bi = blockIdx.x;               // 0..702
  const int tid = threadIdx.x;
  const int wv = tid >> 6, lane = tid & 63;
  const int n16 = lane & 15, quad = lane >> 4;
  const size_t r0 = 256 + (size_t)bi * 128 + (size_t)wv * 32;

  f32x4 acc[2][4];
  #pragma unroll
  for (int mt = 0; mt < 2; ++mt)
    #pragma unroll
    for (int nt = 0; nt < 4; ++nt) acc[mt][nt] = f32x4{0.f, 0.f, 0.f, 0.f};

  const __bf16* arow0 = h_all + (r0 + n16) * 512 + quad * 8;
  const __bf16* arow1 = arow0 + 16 * 512;
  const __bf16* brow  = decW_bf + (size_t)n16 * 512 + quad * 8;

  #pragma unroll
  for (int kc = 0; kc < 16; ++kc) {
    bf16x8 a0 = *(const bf16x8*)(arow0 + kc * 32);
    bf16x8 a1 = *(const bf16x8*)(arow1 + kc * 32);
    #pragma unroll
    for (int nt = 0; nt < 4; ++nt) {
      bf16x8 b = *(const bf16x8*)(brow + (size_t)nt * 8192 + kc * 32);
      acc[0][nt] = __builtin_amdgcn_mfma_f32_16x16x32_bf16(a0, b, acc[0][nt], 0, 0, 0);
      acc[1][nt] = __builtin_amdgcn_mfma_f32_16x16x32_bf16(a1, b, acc[1][nt], 0, 0, 0);
    }
  }
  #pragma unroll
  for (int mt = 0; mt < 2; ++mt)
    #pragma unroll
    for (int nt = 0; nt < 4; ++nt)
      #pragma unroll
      for (int r = 0; r < 4; ++r) {
        size_t R = r0 + mt * 16 + quad * 4 + r;      // h_all row
        int slot = (int)(R >> 7), b = (int)(R & 127);
        int j = slot - 2;
        int c = nt * 16 + n16;
        out[((size_t)b * 703 + j) * 64 + c] = acc[mt][nt][r] + decb[c];
      }
}

// ---------------------------------------------------------------------------
extern "C" void kernel_launch(void* const* d_in, const int* in_sizes, int n_in,
                              void* d_out, int out_size, void* d_ws, size_t ws_size,
                              hipStream_t stream)
{
  const float* x    = (const float*)d_in[0];
  const float* encW = (const float*)d_in[1];
  const float* encb = (const float*)d_in[2];
  const float* Wih  = (const float*)d_in[3];
  const float* Whh  = (const float*)d_in[4];
  const float* bih  = (const float*)d_in[5];
  const float* bhh  = (const float*)d_in[6];
  const float* decW = (const float*)d_in[7];
  const float* decb = (const float*)d_in[8];
  float* out = (float*)d_out;

  if (ws_size < WS_NEEDED) return;

  char* ws = (char*)d_ws;
  __bf16* h_all   = (__bf16*)(ws + OFF_HALL);
  __bf16* Wcat    = (__bf16*)(ws + OFF_WCAT);
  __bf16* Wih_bf  = (__bf16*)(ws + OFF_WIH);
  __bf16* decW_bf = (__bf16*)(ws + OFF_DECW);
  __bf16* xT      = (__bf16*)(ws + OFF_XT);
  float*  b2      = (float*)(ws + OFF_B2);
  float*  b_ar    = (float*)(ws + OFF_BAR_);

  hipLaunchKernelGGL(setup0, dim3(2048), dim3(256), 0, stream,
                     x, Wih, Whh, bih, bhh, decW, xT, Wih_bf, Wcat, decW_bf,
                     b_ar, h_all);
  hipLaunchKernelGGL(setup1, dim3(2048), dim3(64), 0, stream,
                     Wih, encW, encb, bih, bhh, Wcat, b2);
  hipLaunchKernelGGL(lstm_persist, dim3(64), dim3(512), 0, stream,
                     xT, Wcat, Wih_bf, b2, b_ar, h_all);
  hipLaunchKernelGGL(final_proj, dim3(703), dim3(256), 0, stream,
                     h_all, decW_bf, decb, out);
}

// Round 2
// 1839.684 us; speedup vs baseline: 1.8786x; 1.8786x over previous
//
#include <hip/hip_runtime.h>
#include <cstdint>
#include <cstddef>

// ============================================================================
// LSTM forecaster, MI355X — R6: R4 skeleton (1024 thr, 16 waves, full-line
// publish) + R5's operand-swapped interleaved-gate MFMA.
// R5 post-mortem: shfl-publish of 16B fragments doubled HBM writes (90->180MB,
// partial-line writebacks) and 8-wave blocks halved occupancy -> +40% time.
// R6: wave owns 4 feats x 4 gates (16 interleaved weight rows). mfma(wf, af)
// puts {i,f,g,o} of one (feature,batch) in the 4 acc regs -> gate math is
// per-lane VALU on ALL 1024 threads (R4 did it on 256 via 17KB f32 ex[]).
// h goes through a 2KB bf16 hb[] so publish stays R4-coalesced: 256 threads,
// 16 consecutive lanes cover a full 128B line with 8B agent-scope atomics.
// Comm scheme unchanged: bf16 NaN sentinel, 8B relaxed atomics, 2 barriers.
// ============================================================================

typedef __bf16 bf16x8 __attribute__((ext_vector_type(8)));
typedef float  f32x4  __attribute__((ext_vector_type(4)));

static constexpr unsigned long long SENT = 0x7FC07FC07FC07FC0ULL;  // 4x bf16 NaN

// ---- workspace layout (bytes) ----
static constexpr size_t SZ_HALL = (size_t)705 * 128 * 512 * 2;  // h slots 0..704
static constexpr size_t SZ_WCAT = (size_t)2048 * 576 * 2;       // [Whh | Wfuse] bf16
static constexpr size_t SZ_WIH  = (size_t)2048 * 512 * 2;       // Wih bf16 (AR phase)
static constexpr size_t SZ_DECW = (size_t)64 * 512 * 2;         // dec_W bf16
static constexpr size_t SZ_XT   = (size_t)512 * 128 * 64 * 2;   // x transposed [t][b][c]
static constexpr size_t OFF_HALL = 0;
static constexpr size_t OFF_WCAT = OFF_HALL + SZ_HALL;
static constexpr size_t OFF_WIH  = OFF_WCAT + SZ_WCAT;
static constexpr size_t OFF_DECW = OFF_WIH + SZ_WIH;
static constexpr size_t OFF_XT   = OFF_DECW + SZ_DECW;
static constexpr size_t OFF_B2   = OFF_XT + SZ_XT;              // 2048 f32
static constexpr size_t OFF_BAR_ = OFF_B2 + 2048 * 4;           // b_ar 2048 f32
static constexpr size_t WS_NEEDED = OFF_BAR_ + 2048 * 4;

__device__ __forceinline__ float sigm(float x) { return 1.f / (1.f + __expf(-x)); }
__device__ __forceinline__ float tanh_fast(float x) {
  return 1.f - 2.f / (__expf(2.f * x) + 1.f);  // correct +/-1 limits on over/underflow
}

// ---------------------------------------------------------------------------
// setup0: conversions + h slot0 zeros + h slots 1..704 NaN sentinel fill.
// ---------------------------------------------------------------------------
__global__ void __launch_bounds__(256)
setup0(const float* __restrict__ x, const float* __restrict__ Wih,
       const float* __restrict__ Whh, const float* __restrict__ bih,
       const float* __restrict__ bhh, const float* __restrict__ decW,
       __bf16* __restrict__ xT, __bf16* __restrict__ Wih_bf,
       __bf16* __restrict__ Wcat, __bf16* __restrict__ decW_bf,
       float* __restrict__ b_ar, __bf16* __restrict__ h_all)
{
  size_t gid = (size_t)blockIdx.x * blockDim.x + threadIdx.x;
  size_t gsz = (size_t)gridDim.x * blockDim.x;
  for (size_t i = gid; i < 4194304u; i += gsz) {          // xT[t][b][c] = x[b][t][c]
    size_t t = i >> 13, b = (i >> 6) & 127u, c = i & 63u;
    xT[i] = (__bf16)x[(b * 512 + t) * 64 + c];
  }
  for (size_t i = gid; i < 1048576u; i += gsz) Wih_bf[i] = (__bf16)Wih[i];
  for (size_t i = gid; i < 1048576u; i += gsz) {
    size_t r = i >> 9, k = i & 511u;
    Wcat[r * 576 + k] = (__bf16)Whh[i];                   // cols 0..511 = Whh
  }
  for (size_t i = gid; i < 32768u; i += gsz) decW_bf[i] = (__bf16)decW[i];
  for (size_t i = gid; i < 2048u; i += gsz) b_ar[i] = bih[i] + bhh[i];
  unsigned long long* hp = (unsigned long long*)h_all;
  for (size_t i = gid; i < 16384u; i += gsz) hp[i] = 0ULL;               // slot 0 = 0
  for (size_t i = 16384u + gid; i < 11550720u; i += gsz) hp[i] = SENT;   // slots 1..704
}

// ---------------------------------------------------------------------------
// setup1: Wfuse = Wih @ enc_W -> Wcat cols 512..575 ; b2 = bih+bhh+Wih@enc_b
// ---------------------------------------------------------------------------
__global__ void __launch_bounds__(64)
setup1(const float* __restrict__ Wih, const float* __restrict__ encW,
       const float* __restrict__ encb, const float* __restrict__ bih,
       const float* __restrict__ bhh, __bf16* __restrict__ Wcat,
       float* __restrict__ b2)
{
  int r = blockIdx.x;        // 0..2047
  int c = threadIdx.x;       // 0..63
  const float* wr = Wih + (size_t)r * 512;
  float acc = 0.f;
  for (int k = 0; k < 512; ++k) acc += wr[k] * encW[(size_t)k * 64 + c];
  Wcat[(size_t)r * 576 + 512 + c] = (__bf16)acc;
  float p = 0.f;
  for (int kk = 0; kk < 8; ++kk) { int k = kk * 64 + c; p += wr[k] * encb[k]; }
  for (int off = 32; off > 0; off >>= 1) p += __shfl_down(p, off);
  if (c == 0) b2[r] = bih[r] + bhh[r] + p;
}

// ---------------------------------------------------------------------------
// One LSTM step. block = 1024 thr (16 waves). Wave wv owns features
// f0+wv*4 .. +4 across all 4 gates: weight tile rows = f_local*4 + gate
// (f_local = n16>>2, gate = n16&3 at load time). mfma(wf, af):
//   D reg axis r = tile row quad*4+r -> f_local = quad, gate = r
//   D col axis   = activation row n16 -> batch
// so acc = {i,f,g,o} preacts of ONE (feature = f0+wv*4+quad, batch = n16):
// gate math is pure per-lane register code on all 1024 threads.
// h -> hb[16][68] bf16 (2KB, <=2-way bank), barrier, then R4-style publish:
// tid<256, em=tid>>4 batch, p=tid&15 -> 16 lanes = one full 128B line.
// ---------------------------------------------------------------------------
template<bool MAIN>
__device__ __forceinline__ void lstm_step(
    unsigned t, int tid, int wv, int lane, int n16, int quad, int b0, int f0,
    const bf16x8 (&wf)[18], const f32x4& bv,
    __bf16* __restrict__ h_all, const __bf16* __restrict__ xT,
    float& creg, __bf16 (&A)[16][584], __bf16 (&hb)[16][68])
{
  // ---- x prefetch (overlaps the poll) ----
  uint4 xv;
  if (MAIN && tid < 128)
    xv = *(const uint4*)(xT + (size_t)(t - 1) * 8192 +
                         (size_t)(b0 + (tid >> 3)) * 64 + (tid & 7) * 8);

  // ---- poll h_{t-1}: 2 x 8B pieces per thread, selective re-load ----
  const unsigned long long* src = (const unsigned long long*)
      (h_all + (size_t)(t - 1) * 65536 + (size_t)(b0 + (tid >> 6)) * 512) +
      (size_t)(tid & 63) * 2;
  unsigned long long v0 = __hip_atomic_load(src,     __ATOMIC_RELAXED, __HIP_MEMORY_SCOPE_AGENT);
  unsigned long long v1 = __hip_atomic_load(src + 1, __ATOMIC_RELAXED, __HIP_MEMORY_SCOPE_AGENT);
  while (v0 == SENT || v1 == SENT) {
    if (v0 == SENT) v0 = __hip_atomic_load(src,     __ATOMIC_RELAXED, __HIP_MEMORY_SCOPE_AGENT);
    if (v1 == SENT) v1 = __hip_atomic_load(src + 1, __ATOMIC_RELAXED, __HIP_MEMORY_SCOPE_AGENT);
  }

  // ---- stage A (data already in registers from the poll) ----
  {
    unsigned long long* ad = (unsigned long long*)&A[tid >> 6][(tid & 63) * 8];
    ad[0] = v0; ad[1] = v1;
  }
  if (MAIN && tid < 128)
    *(uint4*)(&A[tid >> 3][512 + (tid & 7) * 8]) = xv;
  __syncthreads();

  // ---- MFMA: acc regs = 4 gates of this lane's (feature, batch) ----
  f32x4 a0 = bv, a1 = {0.f, 0.f, 0.f, 0.f};
  const __bf16* arow = &A[n16][quad * 8];
  #pragma unroll
  for (int kc = 0; kc < (MAIN ? 18 : 16); ++kc) {
    bf16x8 af = *(const bf16x8*)(arow + kc * 32);
    if (kc & 1) a1 = __builtin_amdgcn_mfma_f32_16x16x32_bf16(wf[kc], af, a1, 0, 0, 0);
    else        a0 = __builtin_amdgcn_mfma_f32_16x16x32_bf16(wf[kc], af, a0, 0, 0, 0);
  }
  a0 += a1;

  // ---- gates in registers ----
  float ig = sigm(a0[0]), gg = tanh_fast(a0[2]), og = sigm(a0[3]);
  float c2;
  if (MAIN) { float fg = sigm(a0[1]); c2 = fg * creg + ig * gg; creg = c2; }
  else      { c2 = ig * gg; }                      // AR: zero state
  hb[n16][wv * 4 + quad] = (__bf16)(og * tanh_fast(c2));
  __syncthreads();

  // ---- publish: tid<256, 16 consecutive lanes = one full 128B line ----
  if (tid < 256) {
    const int em = tid >> 4, p = tid & 15;
    unsigned long long pk = *(const unsigned long long*)&hb[em][p * 4];
    unsigned long long* dst = (unsigned long long*)
        (h_all + (size_t)t * 65536 + (size_t)(b0 + em) * 512 + f0) + p;
    __hip_atomic_store(dst, pk, __ATOMIC_RELAXED, __HIP_MEMORY_SCOPE_AGENT);
  }
  // no trailing barrier: A/hb writes of step t+1 happen only after this
  // step's second barrier (program order), and publish reads (hb) race only
  // with next step's A staging (different LDS regions).
}

__global__ void __launch_bounds__(1024, 4)
lstm_persist(const __bf16* __restrict__ xT, const __bf16* __restrict__ Wcat,
             const __bf16* __restrict__ Wih_bf, const float* __restrict__ b2,
             const float* __restrict__ b_ar, __bf16* __restrict__ h_all)
{
  const int bid = blockIdx.x;                  // 64 blocks
  const int g = bid & 7, sub = bid >> 3;       // group g: blocks {g, 8+g, ...}
  const int b0 = g * 16, f0 = sub * 64;
  const int tid = threadIdx.x;
  const int wv = tid >> 6, lane = tid & 63;
  const int n16 = lane & 15, quad = lane >> 4;

  __shared__ __align__(16) __bf16 A[16][584];  // 16 batch rows x (512 h + 64 x + pad)
  __shared__ __align__(16) __bf16 hb[16][68];  // h gather, padded (row = 136B)

  // persistent weight fragments, interleaved rows: lane n16 holds tile row
  // n16 = f_local*4+gate -> global row gate*512 + f0 + wv*4 + f_local.
  bf16x8 wf[18];
  f32x4 bv;
  {
    const int gate = n16 & 3, fl = n16 >> 2;
    const __bf16* wrow = Wcat + (size_t)(gate * 512 + f0 + wv * 4 + fl) * 576 + quad * 8;
    #pragma unroll
    for (int kc = 0; kc < 18; ++kc) wf[kc] = *(const bf16x8*)(wrow + kc * 32);
    const int fb = f0 + wv * 4 + quad;         // this lane's feature
    bv = f32x4{b2[fb], b2[512 + fb], b2[1024 + fb], b2[1536 + fb]};
  }

  float creg = 0.f;   // cell state of this lane's (feature = f0+wv*4+quad, batch = n16)

  for (unsigned t = 1; t <= 512; ++t)
    lstm_step<true>(t, tid, wv, lane, n16, quad, b0, f0, wf, bv,
                    h_all, xT, creg, A, hb);

  { // AR phase: h feeds Wih with zero recurrent state
    const int gate = n16 & 3, fl = n16 >> 2;
    const __bf16* wrow = Wih_bf + (size_t)(gate * 512 + f0 + wv * 4 + fl) * 512 + quad * 8;
    #pragma unroll
    for (int kc = 0; kc < 16; ++kc) wf[kc] = *(const bf16x8*)(wrow + kc * 32);
    const int fb = f0 + wv * 4 + quad;
    bv = f32x4{b_ar[fb], b_ar[512 + fb], b_ar[1024 + fb], b_ar[1536 + fb]};
  }
  for (unsigned t = 513; t <= 704; ++t)
    lstm_step<false>(t, tid, wv, lane, n16, quad, b0, f0, wf, bv,
                     h_all, xT, creg, A, hb);
}

// ---------------------------------------------------------------------------
// final_proj: out[b][j][c] = h_slot[j+2][b][:] @ dec_W.T + dec_b, j=0..702.
// ---------------------------------------------------------------------------
__global__ void __launch_bounds__(256)
final_proj(const __bf16* __restrict__ h_all, const __bf16* __restrict__ decW_bf,
           const float* __restrict__ decb, float* __restrict__ out)
{
  const int bi = blockIdx.x;               // 0..702
  const int tid = threadIdx.x;
  const int wv = tid >> 6, lane = tid & 63;
  const int n16 = lane & 15, quad = lane >> 4;
  const size_t r0 = 256 + (size_t)bi * 128 + (size_t)wv * 32;

  f32x4 acc[2][4];
  #pragma unroll
  for (int mt = 0; mt < 2; ++mt)
    #pragma unroll
    for (int nt = 0; nt < 4; ++nt) acc[mt][nt] = f32x4{0.f, 0.f, 0.f, 0.f};

  const __bf16* arow0 = h_all + (r0 + n16) * 512 + quad * 8;
  const __bf16* arow1 = arow0 + 16 * 512;
  const __bf16* brow  = decW_bf + (size_t)n16 * 512 + quad * 8;

  #pragma unroll
  for (int kc = 0; kc < 16; ++kc) {
    bf16x8 a0 = *(const bf16x8*)(arow0 + kc * 32);
    bf16x8 a1 = *(const bf16x8*)(arow1 + kc * 32);
    #pragma unroll
    for (int nt = 0; nt < 4; ++nt) {
      bf16x8 b = *(const bf16x8*)(brow + (size_t)nt * 8192 + kc * 32);
      acc[0][nt] = __builtin_amdgcn_mfma_f32_16x16x32_bf16(a0, b, acc[0][nt], 0, 0, 0);
      acc[1][nt] = __builtin_amdgcn_mfma_f32_16x16x32_bf16(a1, b, acc[1][nt], 0, 0, 0);
    }
  }
  #pragma unroll
  for (int mt = 0; mt < 2; ++mt)
    #pragma unroll
    for (int nt = 0; nt < 4; ++nt)
      #pragma unroll
      for (int r = 0; r < 4; ++r) {
        size_t R = r0 + mt * 16 + quad * 4 + r;      // h_all row
        int slot = (int)(R >> 7), b = (int)(R & 127);
        int j = slot - 2;
        int c = nt * 16 + n16;
        out[((size_t)b * 703 + j) * 64 + c] = acc[mt][nt][r] + decb[c];
      }
}

// ---------------------------------------------------------------------------
extern "C" void kernel_launch(void* const* d_in, const int* in_sizes, int n_in,
                              void* d_out, int out_size, void* d_ws, size_t ws_size,
                              hipStream_t stream)
{
  const float* x    = (const float*)d_in[0];
  const float* encW = (const float*)d_in[1];
  const float* encb = (const float*)d_in[2];
  const float* Wih  = (const float*)d_in[3];
  const float* Whh  = (const float*)d_in[4];
  const float* bih  = (const float*)d_in[5];
  const float* bhh  = (const float*)d_in[6];
  const float* decW = (const float*)d_in[7];
  const float* decb = (const float*)d_in[8];
  float* out = (float*)d_out;

  if (ws_size < WS_NEEDED) return;

  char* ws = (char*)d_ws;
  __bf16* h_all   = (__bf16*)(ws + OFF_HALL);
  __bf16* Wcat    = (__bf16*)(ws + OFF_WCAT);
  __bf16* Wih_bf  = (__bf16*)(ws + OFF_WIH);
  __bf16* decW_bf = (__bf16*)(ws + OFF_DECW);
  __bf16* xT      = (__bf16*)(ws + OFF_XT);
  float*  b2      = (float*)(ws + OFF_B2);
  float*  b_ar    = (float*)(ws + OFF_BAR_);

  hipLaunchKernelGGL(setup0, dim3(2048), dim3(256), 0, stream,
                     x, Wih, Whh, bih, bhh, decW, xT, Wih_bf, Wcat, decW_bf,
                     b_ar, h_all);
  hipLaunchKernelGGL(setup1, dim3(2048), dim3(64), 0, stream,
                     Wih, encW, encb, bih, bhh, Wcat, b2);
  hipLaunchKernelGGL(lstm_persist, dim3(64), dim3(1024), 0, stream,
                     xT, Wcat, Wih_bf, b2, b_ar, h_all);
  hipLaunchKernelGGL(final_proj, dim3(703), dim3(256), 0, stream,
                     h_all, decW_bf, decb, out);
}

// Round 3
// 1797.869 us; speedup vs baseline: 1.9223x; 1.0233x over previous
//
#include <hip/hip_runtime.h>
#include <cstdint>
#include <cstddef>

// ============================================================================
// LSTM forecaster, MI355X — R7: R6 + split-K wave pairing to halve LDS A-reads.
// R6 evidence: step = 5830 cy; all 16 waves read the SAME 18KB A tile (288KB
// LDS reads/step = ~3000-3400 cy of serialized LDS pipe) while MFMA+VALU are
// only ~700 cy. R7: wave w holds the LOW-K half of tiles {w, w^8} (still 18
// fragments = 72 regs); partner wave w^8 holds the HIGH-K half. Each wave
// reads only its 9 kc chunks of A (144 b128/step, halved), computes two
// partial accumulators, exchanges the other-tile partial through a 16KB LDS
// buffer (one extra barrier), then does gate math for its OWN tile exactly as
// in R6 (same creg / hb / publish / poll structure — proven correct).
// ============================================================================

typedef __bf16 bf16x8 __attribute__((ext_vector_type(8)));
typedef float  f32x4  __attribute__((ext_vector_type(4)));

static constexpr unsigned long long SENT = 0x7FC07FC07FC07FC0ULL;  // 4x bf16 NaN

// ---- workspace layout (bytes) ----
static constexpr size_t SZ_HALL = (size_t)705 * 128 * 512 * 2;  // h slots 0..704
static constexpr size_t SZ_WCAT = (size_t)2048 * 576 * 2;       // [Whh | Wfuse] bf16
static constexpr size_t SZ_WIH  = (size_t)2048 * 512 * 2;       // Wih bf16 (AR phase)
static constexpr size_t SZ_DECW = (size_t)64 * 512 * 2;         // dec_W bf16
static constexpr size_t SZ_XT   = (size_t)512 * 128 * 64 * 2;   // x transposed [t][b][c]
static constexpr size_t OFF_HALL = 0;
static constexpr size_t OFF_WCAT = OFF_HALL + SZ_HALL;
static constexpr size_t OFF_WIH  = OFF_WCAT + SZ_WCAT;
static constexpr size_t OFF_DECW = OFF_WIH + SZ_WIH;
static constexpr size_t OFF_XT   = OFF_DECW + SZ_DECW;
static constexpr size_t OFF_B2   = OFF_XT + SZ_XT;              // 2048 f32
static constexpr size_t OFF_BAR_ = OFF_B2 + 2048 * 4;           // b_ar 2048 f32
static constexpr size_t WS_NEEDED = OFF_BAR_ + 2048 * 4;

__device__ __forceinline__ float sigm(float x) { return 1.f / (1.f + __expf(-x)); }
__device__ __forceinline__ float tanh_fast(float x) {
  return 1.f - 2.f / (__expf(2.f * x) + 1.f);  // correct +/-1 limits on over/underflow
}

// ---------------------------------------------------------------------------
// setup0: conversions + h slot0 zeros + h slots 1..704 NaN sentinel fill.
// ---------------------------------------------------------------------------
__global__ void __launch_bounds__(256)
setup0(const float* __restrict__ x, const float* __restrict__ Wih,
       const float* __restrict__ Whh, const float* __restrict__ bih,
       const float* __restrict__ bhh, const float* __restrict__ decW,
       __bf16* __restrict__ xT, __bf16* __restrict__ Wih_bf,
       __bf16* __restrict__ Wcat, __bf16* __restrict__ decW_bf,
       float* __restrict__ b_ar, __bf16* __restrict__ h_all)
{
  size_t gid = (size_t)blockIdx.x * blockDim.x + threadIdx.x;
  size_t gsz = (size_t)gridDim.x * blockDim.x;
  for (size_t i = gid; i < 4194304u; i += gsz) {          // xT[t][b][c] = x[b][t][c]
    size_t t = i >> 13, b = (i >> 6) & 127u, c = i & 63u;
    xT[i] = (__bf16)x[(b * 512 + t) * 64 + c];
  }
  for (size_t i = gid; i < 1048576u; i += gsz) Wih_bf[i] = (__bf16)Wih[i];
  for (size_t i = gid; i < 1048576u; i += gsz) {
    size_t r = i >> 9, k = i & 511u;
    Wcat[r * 576 + k] = (__bf16)Whh[i];                   // cols 0..511 = Whh
  }
  for (size_t i = gid; i < 32768u; i += gsz) decW_bf[i] = (__bf16)decW[i];
  for (size_t i = gid; i < 2048u; i += gsz) b_ar[i] = bih[i] + bhh[i];
  unsigned long long* hp = (unsigned long long*)h_all;
  for (size_t i = gid; i < 16384u; i += gsz) hp[i] = 0ULL;               // slot 0 = 0
  for (size_t i = 16384u + gid; i < 11550720u; i += gsz) hp[i] = SENT;   // slots 1..704
}

// ---------------------------------------------------------------------------
// setup1: Wfuse = Wih @ enc_W -> Wcat cols 512..575 ; b2 = bih+bhh+Wih@enc_b
// ---------------------------------------------------------------------------
__global__ void __launch_bounds__(64)
setup1(const float* __restrict__ Wih, const float* __restrict__ encW,
       const float* __restrict__ encb, const float* __restrict__ bih,
       const float* __restrict__ bhh, __bf16* __restrict__ Wcat,
       float* __restrict__ b2)
{
  int r = blockIdx.x;        // 0..2047
  int c = threadIdx.x;       // 0..63
  const float* wr = Wih + (size_t)r * 512;
  float acc = 0.f;
  for (int k = 0; k < 512; ++k) acc += wr[k] * encW[(size_t)k * 64 + c];
  Wcat[(size_t)r * 576 + 512 + c] = (__bf16)acc;
  float p = 0.f;
  for (int kk = 0; kk < 8; ++kk) { int k = kk * 64 + c; p += wr[k] * encb[k]; }
  for (int off = 32; off > 0; off >>= 1) p += __shfl_down(p, off);
  if (c == 0) b2[r] = bih[r] + bhh[r] + p;
}

// ---------------------------------------------------------------------------
// One LSTM step. block = 1024 thr (16 waves). Wave w: pair p = w&7, role
// r = w>>3 (0 = low-K half, 1 = high-K half). Wave w holds K-half r of BOTH
// tiles w and w^8 (wfo = own tile w, wfx = other tile w^8), reads only its
// 9 (MAIN) / 8 (AR) kc chunks of A, and produces:
//   ao (bias-init) = own-tile partial,  ax (zero-init) = other-tile partial.
// px exchange: wave w writes ax -> px[p][r]; after barrier adds px[p][r^1]
// into ao -> full preacts {i,f,g,o} of (feature f0+w*4+quad, batch n16).
// Gate math / creg / hb / publish identical to R6 (wave w owns tile w).
// ---------------------------------------------------------------------------
template<bool MAIN>
__device__ __forceinline__ void lstm_step(
    unsigned t, int tid, int wv, int lane, int n16, int quad, int b0, int f0,
    const bf16x8 (&wfo)[9], const bf16x8 (&wfx)[9], const f32x4& bv,
    __bf16* __restrict__ h_all, const __bf16* __restrict__ xT,
    float& creg, __bf16 (&A)[16][584], __bf16 (&hb)[16][68],
    f32x4 (&px)[8][2][64])
{
  const int p = wv & 7, r = wv >> 3;
  const int kb = r * (MAIN ? 9 : 8);         // this wave's kc base
  constexpr int KH = MAIN ? 9 : 8;           // kc chunks per wave

  // ---- x prefetch (overlaps the poll) ----
  uint4 xv;
  if (MAIN && tid < 128)
    xv = *(const uint4*)(xT + (size_t)(t - 1) * 8192 +
                         (size_t)(b0 + (tid >> 3)) * 64 + (tid & 7) * 8);

  // ---- poll h_{t-1}: 2 x 8B pieces per thread, selective re-load ----
  const unsigned long long* src = (const unsigned long long*)
      (h_all + (size_t)(t - 1) * 65536 + (size_t)(b0 + (tid >> 6)) * 512) +
      (size_t)(tid & 63) * 2;
  unsigned long long v0 = __hip_atomic_load(src,     __ATOMIC_RELAXED, __HIP_MEMORY_SCOPE_AGENT);
  unsigned long long v1 = __hip_atomic_load(src + 1, __ATOMIC_RELAXED, __HIP_MEMORY_SCOPE_AGENT);
  while (v0 == SENT || v1 == SENT) {
    if (v0 == SENT) v0 = __hip_atomic_load(src,     __ATOMIC_RELAXED, __HIP_MEMORY_SCOPE_AGENT);
    if (v1 == SENT) v1 = __hip_atomic_load(src + 1, __ATOMIC_RELAXED, __HIP_MEMORY_SCOPE_AGENT);
  }

  // ---- stage A (data already in registers from the poll) ----
  {
    unsigned long long* ad = (unsigned long long*)&A[tid >> 6][(tid & 63) * 8];
    ad[0] = v0; ad[1] = v1;
  }
  if (MAIN && tid < 128)
    *(uint4*)(&A[tid >> 3][512 + (tid & 7) * 8]) = xv;
  __syncthreads();                                          // bar1: A ready

  // ---- MFMA: half-K for two tiles; each wave reads only KH chunks of A ----
  f32x4 ao = bv, ax = {0.f, 0.f, 0.f, 0.f};
  const __bf16* arow = &A[n16][quad * 8 + kb * 32];
  #pragma unroll
  for (int kc = 0; kc < KH; ++kc) {
    bf16x8 af = *(const bf16x8*)(arow + kc * 32);
    ao = __builtin_amdgcn_mfma_f32_16x16x32_bf16(wfo[kc], af, ao, 0, 0, 0);
    ax = __builtin_amdgcn_mfma_f32_16x16x32_bf16(wfx[kc], af, ax, 0, 0, 0);
  }

  // ---- exchange other-tile partial, merge own tile ----
  px[p][r][lane] = ax;
  __syncthreads();                                          // bar2: px ready
  ao += px[p][r ^ 1][lane];

  // ---- gates in registers (own tile = wv, same mapping as R6) ----
  float ig = sigm(ao[0]), gg = tanh_fast(ao[2]), og = sigm(ao[3]);
  float c2;
  if (MAIN) { float fg = sigm(ao[1]); c2 = fg * creg + ig * gg; creg = c2; }
  else      { c2 = ig * gg; }                      // AR: zero state
  hb[n16][wv * 4 + quad] = (__bf16)(og * tanh_fast(c2));
  __syncthreads();                                          // bar3: hb ready

  // ---- publish: tid<256, 16 consecutive lanes = one full 128B line ----
  if (tid < 256) {
    const int em = tid >> 4, pp = tid & 15;
    unsigned long long pk = *(const unsigned long long*)&hb[em][pp * 4];
    unsigned long long* dst = (unsigned long long*)
        (h_all + (size_t)t * 65536 + (size_t)(b0 + em) * 512 + f0) + pp;
    __hip_atomic_store(dst, pk, __ATOMIC_RELAXED, __HIP_MEMORY_SCOPE_AGENT);
  }
  // no trailing barrier: next step's A/px/hb writes are all ordered behind
  // next step's own barriers; this step's reads complete before bar3.
}

__global__ void __launch_bounds__(1024, 4)
lstm_persist(const __bf16* __restrict__ xT, const __bf16* __restrict__ Wcat,
             const __bf16* __restrict__ Wih_bf, const float* __restrict__ b2,
             const float* __restrict__ b_ar, __bf16* __restrict__ h_all)
{
  const int bid = blockIdx.x;                  // 64 blocks
  const int g = bid & 7, sub = bid >> 3;       // group g: blocks {g, 8+g, ...}
  const int b0 = g * 16, f0 = sub * 64;
  const int tid = threadIdx.x;
  const int wv = tid >> 6, lane = tid & 63;
  const int n16 = lane & 15, quad = lane >> 4;

  __shared__ __align__(16) __bf16 A[16][584];  // 16 batch rows x (512 h + 64 x + pad)
  __shared__ __align__(16) __bf16 hb[16][68];  // h gather, padded (row = 136B)
  __shared__ __align__(16) f32x4 px[8][2][64]; // split-K partial exchange (16KB)

  // Weight fragments: wave wv holds K-half (wv>>3) of tiles wv (own) and
  // wv^8 (other). Tile t rows: gate = n16&3, fl = n16>>2 -> global row
  // gate*512 + f0 + t*4 + fl. 9+9 fragments = 72 VGPRs (same as R6's 18).
  bf16x8 wfo[9], wfx[9];
  f32x4 bv;
  {
    const int gate = n16 & 3, fl = n16 >> 2;
    const int kb = (wv >> 3) * 9;
    const __bf16* wro = Wcat + (size_t)(gate * 512 + f0 + wv * 4 + fl) * 576
                        + kb * 32 + quad * 8;
    const __bf16* wrx = Wcat + (size_t)(gate * 512 + f0 + (wv ^ 8) * 4 + fl) * 576
                        + kb * 32 + quad * 8;
    #pragma unroll
    for (int kc = 0; kc < 9; ++kc) {
      wfo[kc] = *(const bf16x8*)(wro + kc * 32);
      wfx[kc] = *(const bf16x8*)(wrx + kc * 32);
    }
    const int fb = f0 + wv * 4 + quad;         // this lane's feature
    bv = f32x4{b2[fb], b2[512 + fb], b2[1024 + fb], b2[1536 + fb]};
  }

  float creg = 0.f;   // cell state of this lane's (feature = f0+wv*4+quad, batch = n16)

  for (unsigned t = 1; t <= 512; ++t)
    lstm_step<true>(t, tid, wv, lane, n16, quad, b0, f0, wfo, wfx, bv,
                    h_all, xT, creg, A, hb, px);

  { // AR phase: h feeds Wih with zero recurrent state; K = 512 -> 8+8 chunks
    const int gate = n16 & 3, fl = n16 >> 2;
    const int kb = (wv >> 3) * 8;
    const __bf16* wro = Wih_bf + (size_t)(gate * 512 + f0 + wv * 4 + fl) * 512
                        + kb * 32 + quad * 8;
    const __bf16* wrx = Wih_bf + (size_t)(gate * 512 + f0 + (wv ^ 8) * 4 + fl) * 512
                        + kb * 32 + quad * 8;
    #pragma unroll
    for (int kc = 0; kc < 8; ++kc) {
      wfo[kc] = *(const bf16x8*)(wro + kc * 32);
      wfx[kc] = *(const bf16x8*)(wrx + kc * 32);
    }
    const int fb = f0 + wv * 4 + quad;
    bv = f32x4{b_ar[fb], b_ar[512 + fb], b_ar[1024 + fb], b_ar[1536 + fb]};
  }
  for (unsigned t = 513; t <= 704; ++t)
    lstm_step<false>(t, tid, wv, lane, n16, quad, b0, f0, wfo, wfx, bv,
                     h_all, xT, creg, A, hb, px);
}

// ---------------------------------------------------------------------------
// final_proj: out[b][j][c] = h_slot[j+2][b][:] @ dec_W.T + dec_b, j=0..702.
// ---------------------------------------------------------------------------
__global__ void __launch_bounds__(256)
final_proj(const __bf16* __restrict__ h_all, const __bf16* __restrict__ decW_bf,
           const float* __restrict__ decb, float* __restrict__ out)
{
  const int bi = blockIdx.x;               // 0..702
  const int tid = threadIdx.x;
  const int wv = tid >> 6, lane = tid & 63;
  const int n16 = lane & 15, quad = lane >> 4;
  const size_t r0 = 256 + (size_t)bi * 128 + (size_t)wv * 32;

  f32x4 acc[2][4];
  #pragma unroll
  for (int mt = 0; mt < 2; ++mt)
    #pragma unroll
    for (int nt = 0; nt < 4; ++nt) acc[mt][nt] = f32x4{0.f, 0.f, 0.f, 0.f};

  const __bf16* arow0 = h_all + (r0 + n16) * 512 + quad * 8;
  const __bf16* arow1 = arow0 + 16 * 512;
  const __bf16* brow  = decW_bf + (size_t)n16 * 512 + quad * 8;

  #pragma unroll
  for (int kc = 0; kc < 16; ++kc) {
    bf16x8 a0 = *(const bf16x8*)(arow0 + kc * 32);
    bf16x8 a1 = *(const bf16x8*)(arow1 + kc * 32);
    #pragma unroll
    for (int nt = 0; nt < 4; ++nt) {
      bf16x8 b = *(const bf16x8*)(brow + (size_t)nt * 8192 + kc * 32);
      acc[0][nt] = __builtin_amdgcn_mfma_f32_16x16x32_bf16(a0, b, acc[0][nt], 0, 0, 0);
      acc[1][nt] = __builtin_amdgcn_mfma_f32_16x16x32_bf16(a1, b, acc[1][nt], 0, 0, 0);
    }
  }
  #pragma unroll
  for (int mt = 0; mt < 2; ++mt)
    #pragma unroll
    for (int nt = 0; nt < 4; ++nt)
      #pragma unroll
      for (int r = 0; r < 4; ++r) {
        size_t R = r0 + mt * 16 + quad * 4 + r;      // h_all row
        int slot = (int)(R >> 7), b = (int)(R & 127);
        int j = slot - 2;
        int c = nt * 16 + n16;
        out[((size_t)b * 703 + j) * 64 + c] = acc[mt][nt][r] + decb[c];
      }
}

// ---------------------------------------------------------------------------
extern "C" void kernel_launch(void* const* d_in, const int* in_sizes, int n_in,
                              void* d_out, int out_size, void* d_ws, size_t ws_size,
                              hipStream_t stream)
{
  const float* x    = (const float*)d_in[0];
  const float* encW = (const float*)d_in[1];
  const float* encb = (const float*)d_in[2];
  const float* Wih  = (const float*)d_in[3];
  const float* Whh  = (const float*)d_in[4];
  const float* bih  = (const float*)d_in[5];
  const float* bhh  = (const float*)d_in[6];
  const float* decW = (const float*)d_in[7];
  const float* decb = (const float*)d_in[8];
  float* out = (float*)d_out;

  if (ws_size < WS_NEEDED) return;

  char* ws = (char*)d_ws;
  __bf16* h_all   = (__bf16*)(ws + OFF_HALL);
  __bf16* Wcat    = (__bf16*)(ws + OFF_WCAT);
  __bf16* Wih_bf  = (__bf16*)(ws + OFF_WIH);
  __bf16* decW_bf = (__bf16*)(ws + OFF_DECW);
  __bf16* xT      = (__bf16*)(ws + OFF_XT);
  float*  b2      = (float*)(ws + OFF_B2);
  float*  b_ar    = (float*)(ws + OFF_BAR_);

  hipLaunchKernelGGL(setup0, dim3(2048), dim3(256), 0, stream,
                     x, Wih, Whh, bih, bhh, decW, xT, Wih_bf, Wcat, decW_bf,
                     b_ar, h_all);
  hipLaunchKernelGGL(setup1, dim3(2048), dim3(64), 0, stream,
                     Wih, encW, encb, bih, bhh, Wcat, b2);
  hipLaunchKernelGGL(lstm_persist, dim3(64), dim3(1024), 0, stream,
                     xT, Wcat, Wih_bf, b2, b_ar, h_all);
  hipLaunchKernelGGL(final_proj, dim3(703), dim3(256), 0, stream,
                     h_all, decW_bf, decb, out);
}

// Round 4
// 1787.164 us; speedup vs baseline: 1.9338x; 1.0060x over previous
//
#include <hip/hip_runtime.h>
#include <cstdint>
#include <cstddef>

// ============================================================================
// LSTM forecaster, MI355X — R8: 2x CU count + 1-barrier step + per-wave publish.
// R7 evidence: step 5650cy; per-CU MFMA pipe ~1100-1400cy + VALU ~1700cy with
// 3 barriers forcing full pipe drains; halving LDS reads bought only 185cy.
// R8: 128 blocks x 512 thr (8 waves), 32 feats/block -> per-CU MFMA/VALU work
// halved across 2x CUs. h re-laid as [t][fq][b][4] (fq = feature-quad) so each
// wave owns whole 128B lines: publish = shfl quad-gather + 16-lane full-line
// store right after gate math (no hb, no px). A double-buffered -> ONE
// __syncthreads per step (was 3). Wave holds one full-K weight tile (72 VGPR).
// Comm semantics unchanged: bf16 NaN sentinel, 8B agent-scope relaxed atomics,
// coalesced 128B poll lines, selective re-load.
// ============================================================================

typedef __bf16 bf16x8 __attribute__((ext_vector_type(8)));
typedef float  f32x4  __attribute__((ext_vector_type(4)));

static constexpr unsigned long long SENT = 0x7FC07FC07FC07FC0ULL;  // 4x bf16 NaN

// ---- workspace layout (bytes) ----
static constexpr size_t SZ_HALL = (size_t)705 * 128 * 512 * 2;  // h slots 0..704
static constexpr size_t SZ_WCAT = (size_t)2048 * 576 * 2;       // [Whh | Wfuse] bf16
static constexpr size_t SZ_WIH  = (size_t)2048 * 512 * 2;       // Wih bf16 (AR phase)
static constexpr size_t SZ_DECW = (size_t)64 * 512 * 2;         // dec_W bf16
static constexpr size_t SZ_XT   = (size_t)512 * 128 * 64 * 2;   // x transposed [t][b][c]
static constexpr size_t OFF_HALL = 0;
static constexpr size_t OFF_WCAT = OFF_HALL + SZ_HALL;
static constexpr size_t OFF_WIH  = OFF_WCAT + SZ_WCAT;
static constexpr size_t OFF_DECW = OFF_WIH + SZ_WIH;
static constexpr size_t OFF_XT   = OFF_DECW + SZ_DECW;
static constexpr size_t OFF_B2   = OFF_XT + SZ_XT;              // 2048 f32
static constexpr size_t OFF_BAR_ = OFF_B2 + 2048 * 4;           // b_ar 2048 f32
static constexpr size_t WS_NEEDED = OFF_BAR_ + 2048 * 4;

__device__ __forceinline__ float sigm(float x) { return 1.f / (1.f + __expf(-x)); }
__device__ __forceinline__ float tanh_fast(float x) {
  return 1.f - 2.f / (__expf(2.f * x) + 1.f);  // correct +/-1 limits on over/underflow
}

// h element (t, b, f) lives at h_all[t*65536 + (f>>2)*512 + b*4 + (f&3)]
// -> one 128B line = [t][fq][b0..b0+15][0..3]: 16 batches x 4 feats, owned by
//    exactly one producer wave.

// ---------------------------------------------------------------------------
// setup0: conversions + h slot0 zeros + h slots 1..704 NaN sentinel fill.
// (layout-agnostic byte fills; zero is zero in any layout.)
// ---------------------------------------------------------------------------
__global__ void __launch_bounds__(256)
setup0(const float* __restrict__ x, const float* __restrict__ Wih,
       const float* __restrict__ Whh, const float* __restrict__ bih,
       const float* __restrict__ bhh, const float* __restrict__ decW,
       __bf16* __restrict__ xT, __bf16* __restrict__ Wih_bf,
       __bf16* __restrict__ Wcat, __bf16* __restrict__ decW_bf,
       float* __restrict__ b_ar, __bf16* __restrict__ h_all)
{
  size_t gid = (size_t)blockIdx.x * blockDim.x + threadIdx.x;
  size_t gsz = (size_t)gridDim.x * blockDim.x;
  for (size_t i = gid; i < 4194304u; i += gsz) {          // xT[t][b][c] = x[b][t][c]
    size_t t = i >> 13, b = (i >> 6) & 127u, c = i & 63u;
    xT[i] = (__bf16)x[(b * 512 + t) * 64 + c];
  }
  for (size_t i = gid; i < 1048576u; i += gsz) Wih_bf[i] = (__bf16)Wih[i];
  for (size_t i = gid; i < 1048576u; i += gsz) {
    size_t r = i >> 9, k = i & 511u;
    Wcat[r * 576 + k] = (__bf16)Whh[i];                   // cols 0..511 = Whh
  }
  for (size_t i = gid; i < 32768u; i += gsz) decW_bf[i] = (__bf16)decW[i];
  for (size_t i = gid; i < 2048u; i += gsz) b_ar[i] = bih[i] + bhh[i];
  unsigned long long* hp = (unsigned long long*)h_all;
  for (size_t i = gid; i < 16384u; i += gsz) hp[i] = 0ULL;               // slot 0 = 0
  for (size_t i = 16384u + gid; i < 11550720u; i += gsz) hp[i] = SENT;   // slots 1..704
}

// ---------------------------------------------------------------------------
// setup1: Wfuse = Wih @ enc_W -> Wcat cols 512..575 ; b2 = bih+bhh+Wih@enc_b
// ---------------------------------------------------------------------------
__global__ void __launch_bounds__(64)
setup1(const float* __restrict__ Wih, const float* __restrict__ encW,
       const float* __restrict__ encb, const float* __restrict__ bih,
       const float* __restrict__ bhh, __bf16* __restrict__ Wcat,
       float* __restrict__ b2)
{
  int r = blockIdx.x;        // 0..2047
  int c = threadIdx.x;       // 0..63
  const float* wr = Wih + (size_t)r * 512;
  float acc = 0.f;
  for (int k = 0; k < 512; ++k) acc += wr[k] * encW[(size_t)k * 64 + c];
  Wcat[(size_t)r * 576 + 512 + c] = (__bf16)acc;
  float p = 0.f;
  for (int kk = 0; kk < 8; ++kk) { int k = kk * 64 + c; p += wr[k] * encb[k]; }
  for (int off = 32; off > 0; off >>= 1) p += __shfl_down(p, off);
  if (c == 0) b2[r] = bih[r] + bhh[r] + p;
}

// ---------------------------------------------------------------------------
// One LSTM step. block = 512 thr (8 waves). Block (g,sub): batches b0..b0+16,
// features f0..f0+32 (f0 = sub*32). Wave wv owns feats f0+wv*4..+4 x 4 gates
// as one interleaved weight tile (rows = f_local*4+gate). mfma(wf, af):
//   acc = {i,f,g,o} preacts of (feature = f0+wv*4+quad, batch = b0+n16).
// Poll: thread (wv,quad,n16) loads 4 pieces fq = wv*16+quad*4+j, b = b0+n16
// (16 consecutive lanes = one 128B line, coalesced). Stage: 4 ull = 32B
// contiguous in A[n16][wv*64+quad*16]. ONE barrier; A double-buffered so next
// step's staging (after this step's publish, hence after this bar) can't race
// this step's ds_reads.
// Publish: shfl quad-gather -> lanes 0..15 store one full 128B line of fq =
// f0/4+wv, then straight into the next poll (fire-and-forget store).
// ---------------------------------------------------------------------------
template<bool MAIN>
__device__ __forceinline__ void lstm_step(
    unsigned t, int tid, int wv, int lane, int n16, int quad, int b0, int f0,
    const bf16x8 (&wf)[18], const f32x4& bv,
    __bf16* __restrict__ h_all, const __bf16* __restrict__ xT,
    float& creg, __bf16 (*A)[584])
{
  // ---- x prefetch (overlaps the poll) ----
  uint4 xv;
  if (MAIN && tid < 128)
    xv = *(const uint4*)(xT + (size_t)(t - 1) * 8192 +
                         (size_t)(b0 + (tid >> 3)) * 64 + (tid & 7) * 8);

  // ---- poll h_{t-1}: 4 x 8B pieces (4 consecutive fq, same b), selective ----
  const unsigned long long* s0 = (const unsigned long long*)
      (h_all + (size_t)(t - 1) * 65536) +
      (size_t)(wv * 16 + (quad << 2)) * 128 + (b0 + n16);
  unsigned long long v0 = __hip_atomic_load(s0,       __ATOMIC_RELAXED, __HIP_MEMORY_SCOPE_AGENT);
  unsigned long long v1 = __hip_atomic_load(s0 + 128, __ATOMIC_RELAXED, __HIP_MEMORY_SCOPE_AGENT);
  unsigned long long v2 = __hip_atomic_load(s0 + 256, __ATOMIC_RELAXED, __HIP_MEMORY_SCOPE_AGENT);
  unsigned long long v3 = __hip_atomic_load(s0 + 384, __ATOMIC_RELAXED, __HIP_MEMORY_SCOPE_AGENT);
  while (v0 == SENT || v1 == SENT || v2 == SENT || v3 == SENT) {
    if (v0 == SENT) v0 = __hip_atomic_load(s0,       __ATOMIC_RELAXED, __HIP_MEMORY_SCOPE_AGENT);
    if (v1 == SENT) v1 = __hip_atomic_load(s0 + 128, __ATOMIC_RELAXED, __HIP_MEMORY_SCOPE_AGENT);
    if (v2 == SENT) v2 = __hip_atomic_load(s0 + 256, __ATOMIC_RELAXED, __HIP_MEMORY_SCOPE_AGENT);
    if (v3 == SENT) v3 = __hip_atomic_load(s0 + 384, __ATOMIC_RELAXED, __HIP_MEMORY_SCOPE_AGENT);
  }

  // ---- stage A: pieces fq..fq+3 -> features fq*4..fq*4+16 of batch n16 ----
  {
    unsigned long long* ad = (unsigned long long*)&A[n16][wv * 64 + (quad << 4)];
    ad[0] = v0; ad[1] = v1; ad[2] = v2; ad[3] = v3;
  }
  if (MAIN && tid < 128)
    *(uint4*)(&A[tid >> 3][512 + (tid & 7) * 8]) = xv;
  __syncthreads();                               // the ONLY barrier per step

  // ---- MFMA: acc regs = 4 gates of this lane's (feature, batch) ----
  f32x4 a0 = bv, a1 = {0.f, 0.f, 0.f, 0.f};
  const __bf16* arow = &A[n16][quad * 8];
  #pragma unroll
  for (int kc = 0; kc < (MAIN ? 18 : 16); ++kc) {
    bf16x8 af = *(const bf16x8*)(arow + kc * 32);
    if (kc & 1) a1 = __builtin_amdgcn_mfma_f32_16x16x32_bf16(wf[kc], af, a1, 0, 0, 0);
    else        a0 = __builtin_amdgcn_mfma_f32_16x16x32_bf16(wf[kc], af, a0, 0, 0, 0);
  }
  a0 += a1;

  // ---- gates in registers ----
  float ig = sigm(a0[0]), gg = tanh_fast(a0[2]), og = sigm(a0[3]);
  float c2;
  if (MAIN) { float fg = sigm(a0[1]); c2 = fg * creg + ig * gg; creg = c2; }
  else      { c2 = ig * gg; }                      // AR: zero state
  unsigned hbits = __builtin_bit_cast(unsigned short, (__bf16)(og * tanh_fast(c2)));

  // ---- quad-gather (feat j at bits 16j) + full-line publish by 16 lanes ----
  unsigned long long pk = 0;
  #pragma unroll
  for (int q = 0; q < 4; ++q)
    pk |= (unsigned long long)(unsigned short)__shfl((int)hbits, q * 16 + n16) << (16 * q);
  if (lane < 16) {
    const int fq = (f0 >> 2) + wv;
    unsigned long long* dst = (unsigned long long*)
        (h_all + (size_t)t * 65536) + (size_t)fq * 128 + (b0 + lane);
    __hip_atomic_store(dst, pk, __ATOMIC_RELAXED, __HIP_MEMORY_SCOPE_AGENT);
  }
  // next step's staging writes go to the OTHER A buffer; its barrier orders
  // them against this step's ds_reads.
}

__global__ void __launch_bounds__(512, 2)
lstm_persist(const __bf16* __restrict__ xT, const __bf16* __restrict__ Wcat,
             const __bf16* __restrict__ Wih_bf, const float* __restrict__ b2,
             const float* __restrict__ b_ar, __bf16* __restrict__ h_all)
{
  const int bid = blockIdx.x;                  // 128 blocks
  const int g = bid & 7, sub = bid >> 3;       // sub = 0..15
  const int b0 = g * 16, f0 = sub * 32;
  const int tid = threadIdx.x;
  const int wv = tid >> 6, lane = tid & 63;    // wv = 0..7
  const int n16 = lane & 15, quad = lane >> 4;

  __shared__ __align__(16) __bf16 Abuf[2][16][584];  // double-buffered A tile

  // persistent weight fragments, interleaved rows: lane n16 holds tile row
  // n16 = f_local*4+gate -> global row gate*512 + f0 + wv*4 + f_local.
  bf16x8 wf[18];
  f32x4 bv;
  {
    const int gate = n16 & 3, fl = n16 >> 2;
    const __bf16* wrow = Wcat + (size_t)(gate * 512 + f0 + wv * 4 + fl) * 576 + quad * 8;
    #pragma unroll
    for (int kc = 0; kc < 18; ++kc) wf[kc] = *(const bf16x8*)(wrow + kc * 32);
    const int fb = f0 + wv * 4 + quad;         // this lane's feature
    bv = f32x4{b2[fb], b2[512 + fb], b2[1024 + fb], b2[1536 + fb]};
  }

  float creg = 0.f;   // cell state of (feature = f0+wv*4+quad, batch = b0+n16)

  for (unsigned t = 1; t <= 512; ++t)
    lstm_step<true>(t, tid, wv, lane, n16, quad, b0, f0, wf, bv,
                    h_all, xT, creg, Abuf[t & 1]);

  { // AR phase: h feeds Wih with zero recurrent state
    const int gate = n16 & 3, fl = n16 >> 2;
    const __bf16* wrow = Wih_bf + (size_t)(gate * 512 + f0 + wv * 4 + fl) * 512 + quad * 8;
    #pragma unroll
    for (int kc = 0; kc < 16; ++kc) wf[kc] = *(const bf16x8*)(wrow + kc * 32);
    const int fb = f0 + wv * 4 + quad;
    bv = f32x4{b_ar[fb], b_ar[512 + fb], b_ar[1024 + fb], b_ar[1536 + fb]};
  }
  for (unsigned t = 513; t <= 704; ++t)
    lstm_step<false>(t, tid, wv, lane, n16, quad, b0, f0, wf, bv,
                     h_all, xT, creg, Abuf[t & 1]);
}

// ---------------------------------------------------------------------------
// final_proj: out[b][j][c] = h_slot[j+2][b][:] @ dec_W.T + dec_b, j=0..702.
// h layout [t][fq][b][4]: fragment (slot,b, feats f..f+8) = two 8B pieces at
// ull index slot*16384 + fq*128 + b, fq = f>>2 and fq+1.
// ---------------------------------------------------------------------------
__global__ void __launch_bounds__(256)
final_proj(const __bf16* __restrict__ h_all, const __bf16* __restrict__ decW_bf,
           const float* __restrict__ decb, float* __restrict__ out)
{
  const int bi = blockIdx.x;               // 0..702
  const int tid = threadIdx.x;
  const int wv = tid >> 6, lane = tid & 63;
  const int n16 = lane & 15, quad = lane >> 4;
  const size_t r0 = 256 + (size_t)bi * 128 + (size_t)wv * 32;

  union U8 { unsigned long long u[2]; bf16x8 v; };
  const unsigned long long* hq = (const unsigned long long*)h_all;

  // input-row bases for the two m-tiles (rows r0+n16 and r0+16+n16)
  size_t base[2];
  #pragma unroll
  for (int mt = 0; mt < 2; ++mt) {
    size_t Rm = r0 + (size_t)mt * 16 + n16;
    base[mt] = (Rm >> 7) * 16384 + (Rm & 127);
  }

  f32x4 acc[2][4];
  #pragma unroll
  for (int mt = 0; mt < 2; ++mt)
    #pragma unroll
    for (int nt = 0; nt < 4; ++nt) acc[mt][nt] = f32x4{0.f, 0.f, 0.f, 0.f};

  const __bf16* brow = decW_bf + (size_t)n16 * 512 + quad * 8;

  #pragma unroll
  for (int kc = 0; kc < 16; ++kc) {
    const int fq = quad * 2 + kc * 8;
    U8 a0, a1;
    a0.u[0] = hq[base[0] + (size_t)fq * 128];
    a0.u[1] = hq[base[0] + (size_t)(fq + 1) * 128];
    a1.u[0] = hq[base[1] + (size_t)fq * 128];
    a1.u[1] = hq[base[1] + (size_t)(fq + 1) * 128];
    #pragma unroll
    for (int nt = 0; nt < 4; ++nt) {
      bf16x8 b = *(const bf16x8*)(brow + (size_t)nt * 8192 + kc * 32);
      acc[0][nt] = __builtin_amdgcn_mfma_f32_16x16x32_bf16(a0.v, b, acc[0][nt], 0, 0, 0);
      acc[1][nt] = __builtin_amdgcn_mfma_f32_16x16x32_bf16(a1.v, b, acc[1][nt], 0, 0, 0);
    }
  }
  #pragma unroll
  for (int mt = 0; mt < 2; ++mt)
    #pragma unroll
    for (int nt = 0; nt < 4; ++nt)
      #pragma unroll
      for (int r = 0; r < 4; ++r) {
        size_t R = r0 + mt * 16 + quad * 4 + r;      // h row (slot,b)
        int slot = (int)(R >> 7), b = (int)(R & 127);
        int j = slot - 2;
        int c = nt * 16 + n16;
        out[((size_t)b * 703 + j) * 64 + c] = acc[mt][nt][r] + decb[c];
      }
}

// ---------------------------------------------------------------------------
extern "C" void kernel_launch(void* const* d_in, const int* in_sizes, int n_in,
                              void* d_out, int out_size, void* d_ws, size_t ws_size,
                              hipStream_t stream)
{
  const float* x    = (const float*)d_in[0];
  const float* encW = (const float*)d_in[1];
  const float* encb = (const float*)d_in[2];
  const float* Wih  = (const float*)d_in[3];
  const float* Whh  = (const float*)d_in[4];
  const float* bih  = (const float*)d_in[5];
  const float* bhh  = (const float*)d_in[6];
  const float* decW = (const float*)d_in[7];
  const float* decb = (const float*)d_in[8];
  float* out = (float*)d_out;

  if (ws_size < WS_NEEDED) return;

  char* ws = (char*)d_ws;
  __bf16* h_all   = (__bf16*)(ws + OFF_HALL);
  __bf16* Wcat    = (__bf16*)(ws + OFF_WCAT);
  __bf16* Wih_bf  = (__bf16*)(ws + OFF_WIH);
  __bf16* decW_bf = (__bf16*)(ws + OFF_DECW);
  __bf16* xT      = (__bf16*)(ws + OFF_XT);
  float*  b2      = (float*)(ws + OFF_B2);
  float*  b_ar    = (float*)(ws + OFF_BAR_);

  hipLaunchKernelGGL(setup0, dim3(2048), dim3(256), 0, stream,
                     x, Wih, Whh, bih, bhh, decW, xT, Wih_bf, Wcat, decW_bf,
                     b_ar, h_all);
  hipLaunchKernelGGL(setup1, dim3(2048), dim3(64), 0, stream,
                     Wih, encW, encb, bih, bhh, Wcat, b2);
  hipLaunchKernelGGL(lstm_persist, dim3(128), dim3(512), 0, stream,
                     xT, Wcat, Wih_bf, b2, b_ar, h_all);
  hipLaunchKernelGGL(final_proj, dim3(703), dim3(256), 0, stream,
                     h_all, decW_bf, decb, out);
}